// Round 3
// baseline (336.522 us; speedup 1.0000x reference)
//
#include <hip/hip_runtime.h>

#define NN 1024
#define DD 64
#define CAP 96
#define RCAP 128
#define SENT (NN << 6)   // u16-index of the zeroed dummy G row

// ---- device-global scratch (rewritten every call) ----
__device__ float    WgTd[128*64];     // WgT[k][d] = Wg[d][k]
__device__ float    WsTd[64*64];      // WsT[k][d] = Ws[d][k]
__device__ float    WnTd[64*64];      // WnT[k][d] = Wn[d][k]
__device__ unsigned WnPk[32*64];      // packed bf16 {WnT[2k2][d], WnT[2k2+1][d]}
__device__ float    FSd[NN*DD];       // inputs @ Ws^T + bs
__device__ float    Gd[NN*DD];        // G0 = h0 @ Wn^T (consumed by k_edges only)
__device__ float    preBaseD[NN*DD];  // inputs@Wg1^T + h0@Wg2^T + bg
__device__ float    fpreD[NN*DD];     // sigmoid(FS + G0)
__device__ float4   nodeDatD[NN*DD];  // {fs, preB2, civ, cf2} per (i,d)
__device__ int      lowNeiD[NN*CAP + 64];  // u16-index offsets (j<<6), SENT-padded to 64
__device__ int      revNeiD[NN*RCAP];
__device__ int      revCntD[NN];
__device__ int2     hdrD[NN];         // {lowCnt(<=64), bits(1/num)}
__device__ int      posArr[NN];
__device__ float    invNumD[NN];

__device__ __forceinline__ float sigm(float x)  { return 1.0f / (1.0f + __expf(-x)); }
__device__ __forceinline__ float tanhf_(float x){ return 2.0f / (1.0f + __expf(-2.0f*x)) - 1.0f; }
__device__ __forceinline__ unsigned short bf16r(float x) {
  unsigned u = __float_as_uint(x);
  u = u + 0x7fffu + ((u >> 16) & 1u);
  return (unsigned short)(u >> 16);
}

// ---- K0: pos[], 1/num, revCnt=0, transposes, packed Wn, sentinel fill ----
__global__ __launch_bounds__(256) void k_prep(const int* __restrict__ seq,
                                              const float* __restrict__ numNei,
                                              const float* __restrict__ Wg,
                                              const float* __restrict__ Ws,
                                              const float* __restrict__ Wn) {
  int gid = blockIdx.x * 256 + threadIdx.x;
  if (gid < NN) { posArr[seq[gid]] = gid; invNumD[gid] = 1.0f / numNei[gid]; revCntD[gid] = 0; }
  if (gid < 32*64) {  // packed bf16 WnT pairs, read straight from Wn
    int k2 = gid >> 6, d = gid & 63;
    unsigned lo = bf16r(Wn[d*64 + 2*k2]);
    unsigned hi = bf16r(Wn[d*64 + 2*k2 + 1]);
    WnPk[gid] = lo | (hi << 16);
  }
  #pragma unroll
  for (int q = 0; q < 4; ++q) {  // sentinel-fill first 64 lowNei slots of every node
    int e = gid * 4 + q;
    lowNeiD[(e >> 6) * CAP + (e & 63)] = SENT;
  }
  if (gid < 128*64) {
    int d = gid >> 7, k = gid & 127;
    WgTd[k*64 + d] = Wg[gid];
  } else if (gid < 128*64 + 64*64) {
    int idx = gid - 128*64; int d = idx >> 6, k = idx & 63;
    WsTd[k*64 + d] = Ws[idx];
  } else {
    int idx = gid - (128*64 + 64*64); int d = idx >> 6, k = idx & 63;
    WnTd[k*64 + d] = Wn[idx];
  }
}

// ---- K1: per-node GEMV precompute (1 wave per node) ----
__global__ __launch_bounds__(256) void k_node(const float* __restrict__ inputs,
                                              const float* __restrict__ h0,
                                              const float* __restrict__ bg,
                                              const float* __restrict__ bs) {
  __shared__ float WsT_l[64*64];
  __shared__ float WnT_l[64*64];
  __shared__ float x_l[4][64];
  __shared__ float hh_l[4][64];
  int tid = threadIdx.x;
  for (int idx = tid; idx < 64*64; idx += 256) { WsT_l[idx] = WsTd[idx]; WnT_l[idx] = WnTd[idx]; }
  int w = tid >> 6, d = tid & 63;
  int i = blockIdx.x * 4 + w;
  x_l[w][d]  = inputs[i*DD + d];
  hh_l[w][d] = h0[i*DD + d];
  __syncthreads();
  float afs = bs[d], apre = bg[d], ag0 = 0.0f;
  #pragma unroll 16
  for (int k = 0; k < 64; ++k) {
    float xk = x_l[w][k], hk = hh_l[w][k];
    afs  += xk * WsT_l[k*64 + d];
    ag0  += hk * WnT_l[k*64 + d];
    apre += xk * WgTd[k*64 + d] + hk * WgTd[(64 + k)*64 + d];
  }
  FSd[i*DD + d]      = afs;
  Gd[i*DD + d]       = ag0;
  preBaseD[i*DD + d] = apre;
  fpreD[i*DD + d]    = sigm(afs + ag0);
}

// ---- K2: split neighbors by position; fold future neighbors; build reverse edges ----
__global__ __launch_bounds__(256) void k_edges(const float* __restrict__ adj,
                                               const float* __restrict__ c0) {
  int tid = threadIdx.x;
  int w = tid >> 6, d = tid & 63;
  int i = blockIdx.x * 4 + w;
  int pi = posArr[i];
  float fs = FSd[i*DD + d];
  float accP = 0.0f, accS = 0.0f;
  int cnt = 0;
  for (int base = 0; base < NN; base += 64) {
    float a = adj[i*NN + base + d];
    unsigned long long mask = __ballot(a != 0.0f);
    while (mask) {
      int b = __ffsll(mask) - 1;
      mask &= (mask - 1);
      int j = base + b;
      if (posArr[j] < pi) {
        if (d == 0 && cnt < CAP) {
          lowNeiD[i*CAP + cnt] = j << 6;   // u16-index offset into Gl
          int slot = atomicAdd(&revCntD[j], 1);
          if (slot < RCAP) revNeiD[j*RCAP + slot] = i;
        }
        cnt++;
      } else {
        float g = Gd[j*DD + d];
        accP += g;
        accS += sigm(fs + g);
      }
    }
  }
  float inv = invNumD[i];
  if (d == 0) {
    int ccap = (cnt < 64) ? cnt : 64;
    hdrD[i] = make_int2(ccap, __float_as_int(inv));
  }
  float c0v = c0[i*DD + d];
  float civ = c0v * inv;
  nodeDatD[i*DD + d] = make_float4(fs,
                                   preBaseD[i*DD + d] + accP * inv,
                                   civ,
                                   c0v * fpreD[i*DD + d] + civ * accS);
}

// ---- K3: dataflow scheduler; batched LDS gather; all metadata in LDS ----
__global__ __launch_bounds__(1024, 4) void k_seq(float* __restrict__ out) {
  __shared__ unsigned short Gl[NN*DD + 64];  // bf16 G rows + zeroed dummy row
  __shared__ int   queue_[NN];
  __shared__ int   indeg[NN];
  __shared__ int   meta[NN];                 // cnt | rcnt<<16
  __shared__ float invL[NN];
  __shared__ int   jscr[16][64];             // per-wave neighbor-offset scratch
  __shared__ int   head, tail;
  int tid  = threadIdx.x;
  int lane = tid & 63, w = tid >> 6;
  if (tid == 0) { head = 0; tail = 0; }
  queue_[tid] = -1;
  int2 hdr = hdrD[tid];
  int  rc  = revCntD[tid];
  indeg[tid] = hdr.x;
  meta[tid]  = hdr.x | (rc << 16);
  invL[tid]  = __int_as_float(hdr.y);
  if (tid < 64) Gl[NN*DD + tid] = 0;
  unsigned wvp[32];
  #pragma unroll
  for (int k2 = 0; k2 < 32; ++k2) wvp[k2] = WnPk[k2*64 + lane];
  __syncthreads();
  if (indeg[tid] == 0) {
    int p = __hip_atomic_fetch_add(&tail, 1, __ATOMIC_RELAXED, __HIP_MEMORY_SCOPE_WORKGROUP);
    __hip_atomic_store(&queue_[p], tid, __ATOMIC_RELEASE, __HIP_MEMORY_SCOPE_WORKGROUP);
  }
  __syncthreads();

  for (;;) {
    int t0 = 0;
    if (lane == 0) t0 = __hip_atomic_fetch_add(&head, 1, __ATOMIC_RELAXED, __HIP_MEMORY_SCOPE_WORKGROUP);
    int t = __builtin_amdgcn_readfirstlane(t0);
    if (t >= NN) break;
    int node = __hip_atomic_load(&queue_[t], __ATOMIC_ACQUIRE, __HIP_MEMORY_SCOPE_WORKGROUP);
    while (node < 0)
      node = __hip_atomic_load(&queue_[t], __ATOMIC_ACQUIRE, __HIP_MEMORY_SCOPE_WORKGROUP);
    int i = __builtin_amdgcn_readfirstlane(node);

    int ms   = __builtin_amdgcn_readfirstlane(meta[i]);
    int cnt  = ms & 0xffff;
    int rcnt = ms >> 16;
    float inv = invL[i];
    // issue all global loads up front (concurrent L2 round-trips)
    float4 nd = nodeDatD[i*DD + lane];
    int jb = lowNeiD[i*CAP + lane];
    int r0 = (lane < rcnt)      ? revNeiD[i*RCAP + lane]      : -1;
    int r1 = (lane + 64 < rcnt) ? revNeiD[i*RCAP + 64 + lane] : -1;
    jscr[w][lane] = jb;
    float fs = nd.x;
    float accG = 0.0f, accS = 0.0f;
    for (int base = 0; base < cnt; base += 16) {
      float g[16];
      #pragma unroll
      for (int q = 0; q < 16; ++q) {
        int jq = jscr[w][base + q];          // broadcast ds_read, offset-immediate
        g[q] = __uint_as_float(((unsigned)Gl[jq + lane]) << 16);
      }
      #pragma unroll
      for (int q = 0; q < 16; ++q) {
        bool valid = (base + q) < cnt;       // uniform; cndmask, NaN-safe
        accG += valid ? g[q] : 0.0f;
        float sv = sigm(fs + g[q]);
        accS += valid ? sv : 0.0f;
      }
    }
    float pre = nd.y + inv * accG;
    float is  = sigm(pre);
    float hc  = tanhf_(pre);
    float c   = nd.z * accS + nd.w + is * hc;
    float h   = tanhf_(is * c);
    // G[i] = h @ Wn^T : readlane-broadcast FMAs against packed-bf16 VGPR weights
    unsigned hb = __float_as_uint(h);
    float g0 = 0.f, g1 = 0.f, g2 = 0.f, g3 = 0.f;
    #pragma unroll
    for (int k2 = 0; k2 < 32; k2 += 2) {
      unsigned pw0 = wvp[k2], pw1 = wvp[k2 + 1];
      g0 += __uint_as_float(__builtin_amdgcn_readlane(hb, 2*k2 + 0)) * __uint_as_float(pw0 << 16);
      g1 += __uint_as_float(__builtin_amdgcn_readlane(hb, 2*k2 + 1)) * __uint_as_float(pw0 & 0xffff0000u);
      g2 += __uint_as_float(__builtin_amdgcn_readlane(hb, 2*k2 + 2)) * __uint_as_float(pw1 << 16);
      g3 += __uint_as_float(__builtin_amdgcn_readlane(hb, 2*k2 + 3)) * __uint_as_float(pw1 & 0xffff0000u);
    }
    float gacc = (g0 + g1) + (g2 + g3);
    Gl[(i << 6) + lane] = bf16r(gacc);
    // notify dependents (release orders the Gl write before the push)
    if (r0 >= 0) {
      int old = __hip_atomic_fetch_add(&indeg[r0], -1, __ATOMIC_ACQ_REL, __HIP_MEMORY_SCOPE_WORKGROUP);
      if (old == 1) {
        int p = __hip_atomic_fetch_add(&tail, 1, __ATOMIC_RELAXED, __HIP_MEMORY_SCOPE_WORKGROUP);
        __hip_atomic_store(&queue_[p], r0, __ATOMIC_RELEASE, __HIP_MEMORY_SCOPE_WORKGROUP);
      }
    }
    if (r1 >= 0) {
      int old = __hip_atomic_fetch_add(&indeg[r1], -1, __ATOMIC_ACQ_REL, __HIP_MEMORY_SCOPE_WORKGROUP);
      if (old == 1) {
        int p = __hip_atomic_fetch_add(&tail, 1, __ATOMIC_RELAXED, __HIP_MEMORY_SCOPE_WORKGROUP);
        __hip_atomic_store(&queue_[p], r1, __ATOMIC_RELEASE, __HIP_MEMORY_SCOPE_WORKGROUP);
      }
    }
    // global output store kept OFF the critical notify path
    out[i*DD + lane] = 2.0f * h;
  }
}

extern "C" void kernel_launch(void* const* d_in, const int* in_sizes, int n_in,
                              void* d_out, int out_size, void* d_ws, size_t ws_size,
                              hipStream_t stream) {
  const float* inputs = (const float*)d_in[0];
  const float* adj    = (const float*)d_in[1];
  const float* numNei = (const float*)d_in[2];
  const float* h0     = (const float*)d_in[3];
  const float* c0     = (const float*)d_in[4];
  const float* Wg     = (const float*)d_in[5];
  const float* bg     = (const float*)d_in[6];
  const float* Ws     = (const float*)d_in[7];
  const float* bs     = (const float*)d_in[8];
  const float* Wn     = (const float*)d_in[9];
  const int*   seq    = (const int*)d_in[10];
  float* out = (float*)d_out;

  k_prep <<<64, 256, 0, stream>>>(seq, numNei, Wg, Ws, Wn);
  k_node <<<256, 256, 0, stream>>>(inputs, h0, bg, bs);
  k_edges<<<256, 256, 0, stream>>>(adj, c0);
  k_seq  <<<1, 1024, 0, stream>>>(out);
}

// Round 4
// 256.093 us; speedup vs baseline: 1.3141x; 1.3141x over previous
//
#include <hip/hip_runtime.h>

#define NN 1024
#define DD 64
#define CAP 96
#define RCAP 128
#define SENT (NN << 6)   // u16-index of the -inf dummy G row

typedef __attribute__((ext_vector_type(8))) short bf16x8;
typedef __attribute__((ext_vector_type(4))) float f32x4;

// ---- device-global scratch (rewritten every call) ----
__device__ float    WgTd[128*64];     // WgT[k][d] = Wg[d][k]
__device__ float    WsTd[64*64];      // WsT[k][d] = Ws[d][k]
__device__ float    WnTd[64*64];      // WnT[k][d] = Wn[d][k]
__device__ uint4    WnFragD[8*64];    // MFMA B-fragments: (s*4+t)*64 + lane
__device__ float    FSd[NN*DD];       // inputs @ Ws^T + bs
__device__ float    Gd[NN*DD];        // G0 = h0 @ Wn^T (consumed by k_edges only)
__device__ float    preBaseD[NN*DD];  // inputs@Wg1^T + h0@Wg2^T + bg
__device__ float    fpreD[NN*DD];     // sigmoid(FS + G0)
__device__ float4   nodeDatD[NN*DD];  // {fs, preB2, civ, cf2} per (i,d)
__device__ int      lowNeiD[NN*CAP + 64];  // u16-index offsets (j<<6), SENT-padded to 64
__device__ int      revNeiD[NN*RCAP];
__device__ int      revCntD[NN];
__device__ int2     hdrD[NN];         // {lowCnt(<=64), bits(1/num)}
__device__ int      posArr[NN];
__device__ float    invNumD[NN];

__device__ __forceinline__ float sigm(float x)  { return 1.0f / (1.0f + __expf(-x)); }
__device__ __forceinline__ float tanhf_(float x){ return 2.0f / (1.0f + __expf(-2.0f*x)) - 1.0f; }
__device__ __forceinline__ unsigned short bf16r(float x) {
  unsigned u = __float_as_uint(x);
  u = u + 0x7fffu + ((u >> 16) & 1u);
  return (unsigned short)(u >> 16);
}

// ---- K0: pos[], 1/num, revCnt=0, transposes, MFMA B-frags, sentinel fill ----
__global__ __launch_bounds__(256) void k_prep(const int* __restrict__ seq,
                                              const float* __restrict__ numNei,
                                              const float* __restrict__ Wg,
                                              const float* __restrict__ Ws,
                                              const float* __restrict__ Wn) {
  int gid = blockIdx.x * 256 + threadIdx.x;
  if (gid < NN) { posArr[seq[gid]] = gid; invNumD[gid] = 1.0f / numNei[gid]; revCntD[gid] = 0; }
  if (gid < 512) {  // pack Wn MFMA B-fragments: lane l holds B[8*(l>>4)+j][l&15]
    int st = gid >> 6, lane = gid & 63;
    int s = st >> 2, t = st & 3;
    int row = 16*t + (lane & 15);       // output col index d = 16t + (l&15)
    int k0 = 32*s + 8*(lane >> 4);      // K-slot base (consistent with A staging)
    const float* wr = &Wn[row*64 + k0]; // B[k][d] = WnT[k][d] = Wn[d][k]
    uint4 f;
    f.x = (unsigned)bf16r(wr[0]) | ((unsigned)bf16r(wr[1]) << 16);
    f.y = (unsigned)bf16r(wr[2]) | ((unsigned)bf16r(wr[3]) << 16);
    f.z = (unsigned)bf16r(wr[4]) | ((unsigned)bf16r(wr[5]) << 16);
    f.w = (unsigned)bf16r(wr[6]) | ((unsigned)bf16r(wr[7]) << 16);
    WnFragD[st*64 + lane] = f;
  }
  #pragma unroll
  for (int q = 0; q < 4; ++q) {  // sentinel-fill first 64 lowNei slots of every node
    int e = gid * 4 + q;
    lowNeiD[(e >> 6) * CAP + (e & 63)] = SENT;
  }
  if (gid < 128*64) {
    int d = gid >> 7, k = gid & 127;
    WgTd[k*64 + d] = Wg[gid];
  } else if (gid < 128*64 + 64*64) {
    int idx = gid - 128*64; int d = idx >> 6, k = idx & 63;
    WsTd[k*64 + d] = Ws[idx];
  } else {
    int idx = gid - (128*64 + 64*64); int d = idx >> 6, k = idx & 63;
    WnTd[k*64 + d] = Wn[idx];
  }
}

// ---- K1: per-node GEMV precompute (1 wave per node) ----
__global__ __launch_bounds__(256) void k_node(const float* __restrict__ inputs,
                                              const float* __restrict__ h0,
                                              const float* __restrict__ bg,
                                              const float* __restrict__ bs) {
  __shared__ float WsT_l[64*64];
  __shared__ float WnT_l[64*64];
  __shared__ float x_l[4][64];
  __shared__ float hh_l[4][64];
  int tid = threadIdx.x;
  for (int idx = tid; idx < 64*64; idx += 256) { WsT_l[idx] = WsTd[idx]; WnT_l[idx] = WnTd[idx]; }
  int w = tid >> 6, d = tid & 63;
  int i = blockIdx.x * 4 + w;
  x_l[w][d]  = inputs[i*DD + d];
  hh_l[w][d] = h0[i*DD + d];
  __syncthreads();
  float afs = bs[d], apre = bg[d], ag0 = 0.0f;
  #pragma unroll 16
  for (int k = 0; k < 64; ++k) {
    float xk = x_l[w][k], hk = hh_l[w][k];
    afs  += xk * WsT_l[k*64 + d];
    ag0  += hk * WnT_l[k*64 + d];
    apre += xk * WgTd[k*64 + d] + hk * WgTd[(64 + k)*64 + d];
  }
  FSd[i*DD + d]      = afs;
  Gd[i*DD + d]       = ag0;
  preBaseD[i*DD + d] = apre;
  fpreD[i*DD + d]    = sigm(afs + ag0);
}

// ---- K2: split neighbors by position; fold future neighbors; build reverse edges ----
__global__ __launch_bounds__(256) void k_edges(const float* __restrict__ adj,
                                               const float* __restrict__ c0) {
  int tid = threadIdx.x;
  int w = tid >> 6, d = tid & 63;
  int i = blockIdx.x * 4 + w;
  int pi = posArr[i];
  float fs = FSd[i*DD + d];
  float accP = 0.0f, accS = 0.0f;
  int cnt = 0;
  for (int base = 0; base < NN; base += 64) {
    float a = adj[i*NN + base + d];
    unsigned long long mask = __ballot(a != 0.0f);
    while (mask) {
      int b = __ffsll(mask) - 1;
      mask &= (mask - 1);
      int j = base + b;
      if (posArr[j] < pi) {
        if (d == 0 && cnt < CAP) {
          lowNeiD[i*CAP + cnt] = j << 6;   // u16-index offset into Gl
          int slot = atomicAdd(&revCntD[j], 1);
          if (slot < RCAP) revNeiD[j*RCAP + slot] = i;
        }
        cnt++;
      } else {
        float g = Gd[j*DD + d];
        accP += g;
        accS += sigm(fs + g);
      }
    }
  }
  float inv = invNumD[i];
  if (d == 0) {
    int ccap = (cnt < 64) ? cnt : 64;
    hdrD[i] = make_int2(ccap, __float_as_int(inv));
  }
  float c0v = c0[i*DD + d];
  float civ = c0v * inv;
  nodeDatD[i*DD + d] = make_float4(fs,
                                   preBaseD[i*DD + d] + accP * inv,
                                   civ,
                                   c0v * fpreD[i*DD + d] + civ * accS);
}

// ---- K3: dataflow scheduler; batched LDS gather; MFMA matvec ----
__global__ __launch_bounds__(1024, 4) void k_seq(float* __restrict__ out) {
  __shared__ unsigned short Gl[NN*DD + 64];  // bf16 G rows + (-inf) dummy row
  __shared__ int      queue_[NN];
  __shared__ int      indeg[NN];
  __shared__ int      meta[NN];              // cnt | rcnt<<16
  __shared__ float    invL[NN];
  __shared__ int      jscr[16][64];          // per-wave neighbor-offset scratch
  __shared__ unsigned short hstage[16][64];  // per-wave bf16 h row for MFMA A
  __shared__ int head, tail;
  int tid  = threadIdx.x;
  int lane = tid & 63, w = tid >> 6;
  if (tid == 0) { head = 0; tail = 0; }
  queue_[tid] = -1;
  int2 hdr = hdrD[tid];
  int  rc  = revCntD[tid];
  indeg[tid] = hdr.x;
  meta[tid]  = hdr.x | (rc << 16);
  invL[tid]  = __int_as_float(hdr.y);
  if (tid < 64) Gl[NN*DD + tid] = 0xFF80;    // bf16 -inf sentinel row
  // preload Wn MFMA B-fragments: fb[s][t], 32 VGPRs
  uint4 fb[2][4];
  #pragma unroll
  for (int s = 0; s < 2; ++s)
    #pragma unroll
    for (int t = 0; t < 4; ++t)
      fb[s][t] = WnFragD[(s*4 + t)*64 + lane];
  __syncthreads();
  if (indeg[tid] == 0) {
    int p = __hip_atomic_fetch_add(&tail, 1, __ATOMIC_RELAXED, __HIP_MEMORY_SCOPE_WORKGROUP);
    __hip_atomic_store(&queue_[p], tid, __ATOMIC_RELEASE, __HIP_MEMORY_SCOPE_WORKGROUP);
  }
  __syncthreads();

  for (;;) {
    int t0 = 0;
    if (lane == 0) t0 = __hip_atomic_fetch_add(&head, 1, __ATOMIC_RELAXED, __HIP_MEMORY_SCOPE_WORKGROUP);
    int t = __builtin_amdgcn_readfirstlane(t0);
    if (t >= NN) break;
    int node = __hip_atomic_load(&queue_[t], __ATOMIC_ACQUIRE, __HIP_MEMORY_SCOPE_WORKGROUP);
    while (node < 0)
      node = __hip_atomic_load(&queue_[t], __ATOMIC_ACQUIRE, __HIP_MEMORY_SCOPE_WORKGROUP);
    int i = __builtin_amdgcn_readfirstlane(node);

    int ms   = __builtin_amdgcn_readfirstlane(meta[i]);
    int cnt  = ms & 0xffff;
    int rcnt = ms >> 16;
    float inv = invL[i];
    // issue all global loads up front (concurrent L2 round-trips)
    float4 nd = nodeDatD[i*DD + lane];
    int jb = lowNeiD[i*CAP + lane];
    int r0 = (lane < rcnt)      ? revNeiD[i*RCAP + lane]      : -1;
    int r1 = (lane + 64 < rcnt) ? revNeiD[i*RCAP + 64 + lane] : -1;
    jscr[w][lane] = jb;
    float fs = nd.x;
    float accG = 0.0f, accS = 0.0f;
    for (int base = 0; base < cnt; base += 8) {
      float g[8];
      #pragma unroll
      for (int q = 0; q < 8; ++q) {
        int jq = jscr[w][base + q];          // broadcast ds_read
        g[q] = __uint_as_float(((unsigned)Gl[jq + lane]) << 16);
      }
      #pragma unroll
      for (int q = 0; q < 8; ++q) {
        bool valid = (base + q) < cnt;       // uniform cndmask; pad g = -inf
        accG += valid ? g[q] : 0.0f;
        accS += sigm(fs + g[q]);             // sigm(-inf) == 0 exactly
      }
    }
    float pre = nd.y + inv * accG;
    float is  = sigm(pre);
    float hc  = tanhf_(pre);
    float c   = nd.z * accS + nd.w + is * hc;
    float h   = tanhf_(is * c);
    // ---- G[i] = h @ Wn^T on the MFMA pipe ----
    // stage h as bf16 row; every lane-group reads the same 16B -> all 16 A rows = h
    hstage[w][lane] = bf16r(h);
    const uint4* hv = (const uint4*)&hstage[w][0];
    uint4 fa0 = hv[lane >> 4];        // h[8q .. 8q+7]
    uint4 fa1 = hv[4 + (lane >> 4)];  // h[32+8q .. 32+8q+7]
    f32x4 z = {0.f, 0.f, 0.f, 0.f};
    f32x4 a0 = __builtin_amdgcn_mfma_f32_16x16x32_bf16(__builtin_bit_cast(bf16x8, fa0), __builtin_bit_cast(bf16x8, fb[0][0]), z, 0, 0, 0);
    f32x4 a1 = __builtin_amdgcn_mfma_f32_16x16x32_bf16(__builtin_bit_cast(bf16x8, fa0), __builtin_bit_cast(bf16x8, fb[0][1]), z, 0, 0, 0);
    f32x4 a2 = __builtin_amdgcn_mfma_f32_16x16x32_bf16(__builtin_bit_cast(bf16x8, fa0), __builtin_bit_cast(bf16x8, fb[0][2]), z, 0, 0, 0);
    f32x4 a3 = __builtin_amdgcn_mfma_f32_16x16x32_bf16(__builtin_bit_cast(bf16x8, fa0), __builtin_bit_cast(bf16x8, fb[0][3]), z, 0, 0, 0);
    a0 = __builtin_amdgcn_mfma_f32_16x16x32_bf16(__builtin_bit_cast(bf16x8, fa1), __builtin_bit_cast(bf16x8, fb[1][0]), a0, 0, 0, 0);
    a1 = __builtin_amdgcn_mfma_f32_16x16x32_bf16(__builtin_bit_cast(bf16x8, fa1), __builtin_bit_cast(bf16x8, fb[1][1]), a1, 0, 0, 0);
    a2 = __builtin_amdgcn_mfma_f32_16x16x32_bf16(__builtin_bit_cast(bf16x8, fa1), __builtin_bit_cast(bf16x8, fb[1][2]), a2, 0, 0, 0);
    a3 = __builtin_amdgcn_mfma_f32_16x16x32_bf16(__builtin_bit_cast(bf16x8, fa1), __builtin_bit_cast(bf16x8, fb[1][3]), a3, 0, 0, 0);
    // all rows identical -> lane l holds G[16t + (l&15)] for every tile t in reg 0;
    // select tile t = l>>4 so lane l holds G[l]; one full-wave b16 store.
    float r01 = (lane & 16) ? a1[0] : a0[0];
    float r23 = (lane & 16) ? a3[0] : a2[0];
    float rg  = (lane & 32) ? r23 : r01;
    Gl[(i << 6) + lane] = bf16r(rg);
    // notify dependents (release orders the Gl write before the push)
    if (r0 >= 0) {
      int old = __hip_atomic_fetch_add(&indeg[r0], -1, __ATOMIC_ACQ_REL, __HIP_MEMORY_SCOPE_WORKGROUP);
      if (old == 1) {
        int p = __hip_atomic_fetch_add(&tail, 1, __ATOMIC_RELAXED, __HIP_MEMORY_SCOPE_WORKGROUP);
        __hip_atomic_store(&queue_[p], r0, __ATOMIC_RELEASE, __HIP_MEMORY_SCOPE_WORKGROUP);
      }
    }
    if (r1 >= 0) {
      int old = __hip_atomic_fetch_add(&indeg[r1], -1, __ATOMIC_ACQ_REL, __HIP_MEMORY_SCOPE_WORKGROUP);
      if (old == 1) {
        int p = __hip_atomic_fetch_add(&tail, 1, __ATOMIC_RELAXED, __HIP_MEMORY_SCOPE_WORKGROUP);
        __hip_atomic_store(&queue_[p], r1, __ATOMIC_RELEASE, __HIP_MEMORY_SCOPE_WORKGROUP);
      }
    }
    // global output store kept OFF the critical notify path
    out[i*DD + lane] = 2.0f * h;
  }
}

extern "C" void kernel_launch(void* const* d_in, const int* in_sizes, int n_in,
                              void* d_out, int out_size, void* d_ws, size_t ws_size,
                              hipStream_t stream) {
  const float* inputs = (const float*)d_in[0];
  const float* adj    = (const float*)d_in[1];
  const float* numNei = (const float*)d_in[2];
  const float* h0     = (const float*)d_in[3];
  const float* c0     = (const float*)d_in[4];
  const float* Wg     = (const float*)d_in[5];
  const float* bg     = (const float*)d_in[6];
  const float* Ws     = (const float*)d_in[7];
  const float* bs     = (const float*)d_in[8];
  const float* Wn     = (const float*)d_in[9];
  const int*   seq    = (const int*)d_in[10];
  float* out = (float*)d_out;

  k_prep <<<64, 256, 0, stream>>>(seq, numNei, Wg, Ws, Wn);
  k_node <<<256, 256, 0, stream>>>(inputs, h0, bg, bs);
  k_edges<<<256, 256, 0, stream>>>(adj, c0);
  k_seq  <<<1, 1024, 0, stream>>>(out);
}